// Round 1
// baseline (1721.492 us; speedup 1.0000x reference)
//
#include <hip/hip_runtime.h>
#include <math.h>

#define NN 10000
#define EE 160000
#define H 128
#define LAYERS 3
#define NRBF 20
#define RADIUS 5.0f
#define PI_F 3.14159265358979323846f

__device__ __forceinline__ float clipf(float x){ return fminf(fmaxf(x, -1e4f), 1e4f); }
__device__ __forceinline__ float siluf(float x){ return x / (1.0f + __expf(-x)); }

// ---------------- edge geometry + RBF ----------------
__global__ __launch_bounds__(256) void edge_kernel(const float* __restrict__ ev,
                                                   float* __restrict__ dir,
                                                   float* __restrict__ P){
    int e = blockIdx.x * 256 + threadIdx.x;
    if (e >= EE) return;
    float x = ev[e*3+0], y = ev[e*3+1], z = ev[e*3+2];
    float d = sqrtf(x*x + y*y + z*z + 1e-8f);
    float inv = 1.0f / d;
    dir[0*EE+e] = x*inv; dir[1*EE+e] = y*inv; dir[2*EE+e] = z*inv;
    float cut = (d < RADIUS) ? 0.5f * (__cosf(PI_F * d / RADIUS) + 1.0f) : 0.0f;
    #pragma unroll
    for (int k = 0; k < NRBF; k++){
        float mu = RADIUS * (float)k / (float)(NRBF - 1);
        float t = d - mu;
        P[k*EE+e] = __expf(-8.0f * t * t) * cut;   // gamma = 0.5/(R/NRBF)^2 = 8
    }
    P[NRBF*EE+e] = cut;   // bias row multiplier
}

// ---------------- embedding ----------------
__global__ __launch_bounds__(256) void embed_kernel(const int* __restrict__ z,
                                                    const float* __restrict__ emb,
                                                    float* __restrict__ s){
    int idx = blockIdx.x * 256 + threadIdx.x;
    if (idx >= NN * H) return;
    int n = idx >> 7, h = idx & 127;
    s[idx] = emb[z[n]*H + h];
}

// ---------------- x = silu(s@W1+b1)@W2+b2 ----------------
__global__ __launch_bounds__(256) void xmlp_kernel(const float* __restrict__ s,
                                                   const float* __restrict__ W1, const float* __restrict__ b1,
                                                   const float* __restrict__ W2, const float* __restrict__ b2,
                                                   float* __restrict__ x){
    __shared__ float st[32][H];
    __shared__ float hid[32][H];
    int n0 = blockIdx.x * 32;
    int t = threadIdx.x;
    for (int i = t; i < 32*H; i += 256){
        int r = i >> 7, c = i & 127;
        int n = n0 + r;
        st[r][c] = (n < NN) ? s[n*H + c] : 0.0f;
    }
    __syncthreads();
    int h = t & 127, g = t >> 7;       // g in {0,1}: 16 nodes each
    float acc[16];
    #pragma unroll
    for (int i = 0; i < 16; i++) acc[i] = b1[h];
    for (int k = 0; k < H; k++){
        float w = W1[k*H + h];
        #pragma unroll
        for (int i = 0; i < 16; i++) acc[i] = fmaf(st[g*16+i][k], w, acc[i]);
    }
    #pragma unroll
    for (int i = 0; i < 16; i++) hid[g*16+i][h] = siluf(acc[i]);
    __syncthreads();
    for (int jj = 0; jj < 3; jj++){
        int col = jj*H + h;
        float a2[16];
        #pragma unroll
        for (int i = 0; i < 16; i++) a2[i] = b2[col];
        for (int k = 0; k < H; k++){
            float w = W2[k*384 + col];
            #pragma unroll
            for (int i = 0; i < 16; i++) a2[i] = fmaf(hid[g*16+i][k], w, a2[i]);
        }
        #pragma unroll
        for (int i = 0; i < 16; i++){
            int n = n0 + g*16 + i;
            if (n < NN) x[n*384 + col] = a2[i];
        }
    }
}

// ---------------- message + scatter (atomics) ----------------
__global__ __launch_bounds__(256) void msg_kernel(const float* __restrict__ P, const float* __restrict__ dir,
                                                  const float* __restrict__ x, const float* __restrict__ v,
                                                  const int* __restrict__ send, const int* __restrict__ recv,
                                                  const float* __restrict__ fW, const float* __restrict__ fb,
                                                  float* __restrict__ dsn, float* __restrict__ dvn, int l){
    int t = threadIdx.x;
    int e = blockIdx.x * 2 + (t >> 7);
    if (e >= EE) return;
    int h = t & 127;
    int col0 = l*384 + h;
    float p[21];
    #pragma unroll
    for (int k = 0; k < 21; k++) p[k] = P[k*EE + e];
    float f0 = p[20]*fb[col0], f1 = p[20]*fb[col0+128], f2 = p[20]*fb[col0+256];
    #pragma unroll
    for (int k = 0; k < 20; k++){
        const float* w = fW + k*1152 + col0;
        f0 = fmaf(p[k], w[0],   f0);
        f1 = fmaf(p[k], w[128], f1);
        f2 = fmaf(p[k], w[256], f2);
    }
    int r = recv[e], sn = send[e];
    float mds = f0 * x[r*384 + h];
    float a   = f1 * x[r*384 + 128 + h];
    float b   = f2 * x[r*384 + 256 + h];
    atomicAdd(&dsn[sn*H + h], mds);
    #pragma unroll
    for (int c = 0; c < 3; c++){
        float dv = a * dir[c*EE + e] + b * v[(r*3 + c)*H + h];
        atomicAdd(&dvn[(sn*3 + c)*H + h], dv);
    }
}

// ---------------- v += clip(dv); vl/vr = v @ vW ----------------
__global__ __launch_bounds__(256) void vmix_kernel(float* __restrict__ v, const float* __restrict__ dvn,
                                                   const float* __restrict__ vW,
                                                   float* __restrict__ vl, float* __restrict__ vr){
    __shared__ float vt[32][H];
    int r0 = blockIdx.x * 32;       // row = n*3 + c, total 3N
    int t = threadIdx.x;
    for (int i = t; i < 32*H; i += 256){
        int rr = i >> 7, c = i & 127;
        int row = r0 + rr;
        float val = 0.0f;
        if (row < 3*NN){
            val = v[row*H + c] + clipf(dvn[row*H + c]);
            v[row*H + c] = val;
        }
        vt[rr][c] = val;
    }
    __syncthreads();
    float acc[32];
    #pragma unroll
    for (int i = 0; i < 32; i++) acc[i] = 0.0f;
    for (int k = 0; k < H; k++){
        float w = vW[k*256 + t];
        #pragma unroll
        for (int i = 0; i < 32; i++) acc[i] = fmaf(vt[i][k], w, acc[i]);
    }
    float* dst = (t < 128) ? vl : vr;
    int c = t & 127;
    #pragma unroll
    for (int i = 0; i < 32; i++){
        int row = r0 + i;
        if (row < 3*NN) dst[row*H + c] = acc[i];
    }
}

// ---------------- update / mixing MLP + final writes ----------------
__global__ __launch_bounds__(256) void update_kernel(float* __restrict__ s, float* __restrict__ v,
                                                     const float* __restrict__ dsn,
                                                     const float* __restrict__ vl, const float* __restrict__ vr,
                                                     const float* __restrict__ mW1, const float* __restrict__ mb1,
                                                     const float* __restrict__ mW2, const float* __restrict__ mb2){
    __shared__ float ts[16][256];
    __shared__ float hid[16][H];
    __shared__ float dotl[16][H];
    int n0 = blockIdx.x * 16;
    int t = threadIdx.x;
    for (int idx = t; idx < 16*H; idx += 256){
        int i = idx >> 7, h = idx & 127;
        int n = n0 + i;
        float sm = s[n*H + h] + clipf(dsn[n*H + h]);
        ts[i][h] = sm;
        float l0 = vl[(n*3+0)*H+h], l1 = vl[(n*3+1)*H+h], l2 = vl[(n*3+2)*H+h];
        float r0 = vr[(n*3+0)*H+h], r1 = vr[(n*3+1)*H+h], r2 = vr[(n*3+2)*H+h];
        ts[i][128+h] = sqrtf(l0*l0 + l1*l1 + l2*l2 + 1e-8f);
        dotl[i][h] = l0*r0 + l1*r1 + l2*r2;
    }
    __syncthreads();
    int h = t & 127, g = t >> 7;     // 8 nodes per group
    float acc[8];
    #pragma unroll
    for (int i = 0; i < 8; i++) acc[i] = mb1[h];
    for (int k = 0; k < 256; k++){
        float w = mW1[k*H + h];
        #pragma unroll
        for (int i = 0; i < 8; i++) acc[i] = fmaf(ts[g*8+i][k], w, acc[i]);
    }
    #pragma unroll
    for (int i = 0; i < 8; i++) hid[g*8+i][h] = siluf(acc[i]);
    __syncthreads();
    float m0[8], m1[8], m2[8];
    #pragma unroll
    for (int i = 0; i < 8; i++){ m0[i] = mb2[h]; m1[i] = mb2[128+h]; m2[i] = mb2[256+h]; }
    for (int k = 0; k < H; k++){
        const float* w = mW2 + k*384;
        float w0 = w[h], w1 = w[128+h], w2 = w[256+h];
        #pragma unroll
        for (int i = 0; i < 8; i++){
            float hv = hid[g*8+i][k];
            m0[i] = fmaf(hv, w0, m0[i]);
            m1[i] = fmaf(hv, w1, m1[i]);
            m2[i] = fmaf(hv, w2, m2[i]);
        }
    }
    #pragma unroll
    for (int i = 0; i < 8; i++){
        int n = n0 + g*8 + i;
        s[n*H + h] = ts[g*8+i][h] + clipf(m0[i] + m2[i]*dotl[g*8+i][h]);
        #pragma unroll
        for (int c = 0; c < 3; c++){
            int off = (n*3 + c)*H + h;
            v[off] = v[off] + clipf(m1[i] * vr[off]);
        }
    }
}

extern "C" void kernel_launch(void* const* d_in, const int* in_sizes, int n_in,
                              void* d_out, int out_size, void* d_ws, size_t ws_size,
                              hipStream_t stream) {
    const int*   z    = (const int*)  d_in[0];
    const float* ev   = (const float*)d_in[1];
    const int*   send = (const int*)  d_in[2];
    const int*   recv = (const int*)  d_in[3];
    const float* emb  = (const float*)d_in[4];
    const float* fW   = (const float*)d_in[5];
    const float* fb   = (const float*)d_in[6];
    const float* iW1  = (const float*)d_in[7];
    const float* ib1  = (const float*)d_in[8];
    const float* iW2  = (const float*)d_in[9];
    const float* ib2  = (const float*)d_in[10];
    const float* mW1  = (const float*)d_in[11];
    const float* mb1  = (const float*)d_in[12];
    const float* mW2  = (const float*)d_in[13];
    const float* mb2  = (const float*)d_in[14];
    const float* vW   = (const float*)d_in[15];

    float* s = (float*)d_out;          // [N,H]
    float* v = s + NN*H;               // [N,3,H]

    float* w   = (float*)d_ws;
    float* dir = w;  w += 3*EE;        // [3][E]
    float* P   = w;  w += 21*EE;       // [21][E]
    float* x   = w;  w += NN*384;      // [N,384]
    float* dsn = w;  w += NN*H;        // [N,H]      (contiguous with dvn for one memset)
    float* dvn = w;  w += NN*3*H;      // [N,3,H]
    float* vl  = w;  w += NN*3*H;      // [N,3,H]
    float* vr  = w;  w += NN*3*H;      // [N,3,H]

    edge_kernel<<<(EE+255)/256, 256, 0, stream>>>(ev, dir, P);
    embed_kernel<<<(NN*H+255)/256, 256, 0, stream>>>(z, emb, s);
    hipMemsetAsync(v, 0, (size_t)NN*3*H*sizeof(float), stream);

    for (int l = 0; l < LAYERS; l++){
        hipMemsetAsync(dsn, 0, (size_t)(NN*H + NN*3*H)*sizeof(float), stream);
        xmlp_kernel<<<(NN+31)/32, 256, 0, stream>>>(s, iW1 + l*H*H, ib1 + l*H,
                                                    iW2 + l*H*384, ib2 + l*384, x);
        msg_kernel<<<EE/2, 256, 0, stream>>>(P, dir, x, v, send, recv, fW, fb, dsn, dvn, l);
        vmix_kernel<<<(3*NN+31)/32, 256, 0, stream>>>(v, dvn, vW + l*H*256, vl, vr);
        update_kernel<<<NN/16, 256, 0, stream>>>(s, v, dsn, vl, vr,
                                                 mW1 + l*256*H, mb1 + l*H,
                                                 mW2 + l*H*384, mb2 + l*384);
    }
}

// Round 2
// 1205.587 us; speedup vs baseline: 1.4279x; 1.4279x over previous
//
#include <hip/hip_runtime.h>
#include <math.h>

#define NN 10000
#define EE 160000
#define H 128
#define LAYERS 3
#define NRBF 20
#define RADIUS 5.0f
#define PI_F 3.14159265358979323846f

__device__ __forceinline__ float clipf(float x){ return fminf(fmaxf(x, -1e4f), 1e4f); }
__device__ __forceinline__ float siluf(float x){ return x / (1.0f + __expf(-x)); }

// ---------------- edge geometry + RBF: row = [dir0,dir1,dir2, phi*cut[0..19], cut] ----------------
__global__ __launch_bounds__(256) void edge_kernel(const float* __restrict__ ev,
                                                   float* __restrict__ P){
    int e = blockIdx.x * 256 + threadIdx.x;
    if (e >= EE) return;
    float x = ev[e*3+0], y = ev[e*3+1], z = ev[e*3+2];
    float d = sqrtf(x*x + y*y + z*z + 1e-8f);
    float inv = 1.0f / d;
    float cut = (d < RADIUS) ? 0.5f * (__cosf(PI_F * d / RADIUS) + 1.0f) : 0.0f;
    float row[24];
    row[0] = x*inv; row[1] = y*inv; row[2] = z*inv;
    #pragma unroll
    for (int k = 0; k < NRBF; k++){
        float mu = RADIUS * (float)k / (float)(NRBF - 1);
        float t = d - mu;
        row[3+k] = __expf(-8.0f * t * t) * cut;   // gamma = 0.5/(R/NRBF)^2 = 8
    }
    row[23] = cut;
    float4* dst = (float4*)(P + (size_t)e*24);
    #pragma unroll
    for (int i = 0; i < 6; i++) dst[i] = ((const float4*)row)[i];
}

// ---------------- CSR build ----------------
__global__ __launch_bounds__(256) void hist_kernel(const int* __restrict__ send, int* __restrict__ cnt){
    int e = blockIdx.x * 256 + threadIdx.x;
    if (e < EE) atomicAdd(&cnt[send[e]], 1);
}

__global__ __launch_bounds__(1024) void scan_kernel(const int* __restrict__ cnt,
                                                    int* __restrict__ row_ptr,
                                                    int* __restrict__ cursor){
    __shared__ int part[1024];
    int t = threadIdx.x;
    int base = t * 10;
    int local[10];
    int sum = 0;
    #pragma unroll
    for (int i = 0; i < 10; i++){
        int idx = base + i;
        local[i] = (idx < NN) ? cnt[idx] : 0;
        sum += local[i];
    }
    part[t] = sum;
    __syncthreads();
    for (int off = 1; off < 1024; off <<= 1){
        int val = (t >= off) ? part[t - off] : 0;
        __syncthreads();
        part[t] += val;
        __syncthreads();
    }
    int run = (t > 0) ? part[t-1] : 0;
    #pragma unroll
    for (int i = 0; i < 10; i++){
        int idx = base + i;
        if (idx < NN){ row_ptr[idx] = run; cursor[idx] = run; run += local[i]; }
    }
    if (t == 1023) row_ptr[NN] = part[1023];
}

__global__ __launch_bounds__(256) void scatter_kernel(const int* __restrict__ send,
                                                      int* __restrict__ cursor,
                                                      int* __restrict__ order){
    int e = blockIdx.x * 256 + threadIdx.x;
    if (e < EE){
        int p = atomicAdd(&cursor[send[e]], 1);
        order[p] = e;
    }
}

// ---------------- embedding ----------------
__global__ __launch_bounds__(256) void embed_kernel(const int* __restrict__ z,
                                                    const float* __restrict__ emb,
                                                    float* __restrict__ s){
    int idx = blockIdx.x * 256 + threadIdx.x;
    if (idx >= NN * H) return;
    int n = idx >> 7, h = idx & 127;
    s[idx] = emb[z[n]*H + h];
}

// ---------------- x = silu(s@W1+b1)@W2+b2 ----------------
__global__ __launch_bounds__(256) void xmlp_kernel(const float* __restrict__ s,
                                                   const float* __restrict__ W1, const float* __restrict__ b1,
                                                   const float* __restrict__ W2, const float* __restrict__ b2,
                                                   float* __restrict__ x){
    __shared__ float st[32][H];
    __shared__ float hid[32][H];
    int n0 = blockIdx.x * 32;
    int t = threadIdx.x;
    for (int i = t; i < 32*H; i += 256){
        int r = i >> 7, c = i & 127;
        int n = n0 + r;
        st[r][c] = (n < NN) ? s[n*H + c] : 0.0f;
    }
    __syncthreads();
    int h = t & 127, g = t >> 7;       // g in {0,1}: 16 nodes each
    float acc[16];
    #pragma unroll
    for (int i = 0; i < 16; i++) acc[i] = b1[h];
    for (int k = 0; k < H; k++){
        float w = W1[k*H + h];
        #pragma unroll
        for (int i = 0; i < 16; i++) acc[i] = fmaf(st[g*16+i][k], w, acc[i]);
    }
    #pragma unroll
    for (int i = 0; i < 16; i++) hid[g*16+i][h] = siluf(acc[i]);
    __syncthreads();
    for (int jj = 0; jj < 3; jj++){
        int col = jj*H + h;
        float a2[16];
        #pragma unroll
        for (int i = 0; i < 16; i++) a2[i] = b2[col];
        for (int k = 0; k < H; k++){
            float w = W2[k*384 + col];
            #pragma unroll
            for (int i = 0; i < 16; i++) a2[i] = fmaf(hid[g*16+i][k], w, a2[i]);
        }
        #pragma unroll
        for (int i = 0; i < 16; i++){
            int n = n0 + g*16 + i;
            if (n < NN) x[n*384 + col] = a2[i];
        }
    }
}

// ---------------- message: gather per sender node (no atomics) ----------------
__global__ __launch_bounds__(256) void msg_csr_kernel(const float* __restrict__ P,
                                                      const float* __restrict__ x, const float* __restrict__ v,
                                                      const int* __restrict__ recv,
                                                      const int* __restrict__ row_ptr, const int* __restrict__ order,
                                                      const float* __restrict__ fW, const float* __restrict__ fb,
                                                      float* __restrict__ s, float* __restrict__ dvn, int l){
    int t = threadIdx.x;
    int h = t & 127;
    int n = blockIdx.x * 2 + (t >> 7);
    int col0 = l*384 + h;
    // hoist filter weights for this (h, layer) into registers
    float wf0[NRBF], wf1[NRBF], wf2[NRBF];
    #pragma unroll
    for (int k = 0; k < NRBF; k++){
        const float* w = fW + k*1152 + col0;
        wf0[k] = w[0]; wf1[k] = w[128]; wf2[k] = w[256];
    }
    float b0 = fb[col0], b1 = fb[col0+128], b2 = fb[col0+256];
    if (n >= NN) return;
    int beg = row_ptr[n], end = row_ptr[n+1];
    float ds = 0.0f, dv0 = 0.0f, dv1 = 0.0f, dv2 = 0.0f;
    #pragma unroll 2
    for (int idx = beg; idx < end; idx++){
        int e = order[idx];
        const float4* pe = (const float4*)(P + (size_t)e*24);
        float4 q0 = pe[0], q1 = pe[1], q2 = pe[2], q3 = pe[3], q4 = pe[4], q5 = pe[5];
        int r = recv[e];
        float p[20] = {q0.w, q1.x,q1.y,q1.z,q1.w, q2.x,q2.y,q2.z,q2.w,
                       q3.x,q3.y,q3.z,q3.w, q4.x,q4.y,q4.z,q4.w, q5.x,q5.y,q5.z};
        float cut = q5.w;
        float f0 = b0*cut, f1 = b1*cut, f2 = b2*cut;
        #pragma unroll
        for (int k = 0; k < NRBF; k++){
            f0 = fmaf(p[k], wf0[k], f0);
            f1 = fmaf(p[k], wf1[k], f1);
            f2 = fmaf(p[k], wf2[k], f2);
        }
        const float* xr = x + (size_t)r*384;
        float a = f1 * xr[128 + h];
        float b = f2 * xr[256 + h];
        ds = fmaf(f0, xr[h], ds);
        const float* vr_ = v + (size_t)r*3*H + h;
        dv0 = fmaf(a, q0.x, fmaf(b, vr_[0],   dv0));
        dv1 = fmaf(a, q0.y, fmaf(b, vr_[H],   dv1));
        dv2 = fmaf(a, q0.z, fmaf(b, vr_[2*H], dv2));
    }
    s[n*H + h] += clipf(ds);
    dvn[((size_t)n*3 + 0)*H + h] = dv0;
    dvn[((size_t)n*3 + 1)*H + h] = dv1;
    dvn[((size_t)n*3 + 2)*H + h] = dv2;
}

// ---------------- v += clip(dv); vl/vr = v @ vW ----------------
__global__ __launch_bounds__(256) void vmix_kernel(float* __restrict__ v, const float* __restrict__ dvn,
                                                   const float* __restrict__ vW,
                                                   float* __restrict__ vl, float* __restrict__ vr){
    __shared__ float vt[32][H];
    int r0 = blockIdx.x * 32;       // row = n*3 + c, total 3N
    int t = threadIdx.x;
    for (int i = t; i < 32*H; i += 256){
        int rr = i >> 7, c = i & 127;
        int row = r0 + rr;
        float val = 0.0f;
        if (row < 3*NN){
            val = v[row*H + c] + clipf(dvn[row*H + c]);
            v[row*H + c] = val;
        }
        vt[rr][c] = val;
    }
    __syncthreads();
    float acc[32];
    #pragma unroll
    for (int i = 0; i < 32; i++) acc[i] = 0.0f;
    for (int k = 0; k < H; k++){
        float w = vW[k*256 + t];
        #pragma unroll
        for (int i = 0; i < 32; i++) acc[i] = fmaf(vt[i][k], w, acc[i]);
    }
    float* dst = (t < 128) ? vl : vr;
    int c = t & 127;
    #pragma unroll
    for (int i = 0; i < 32; i++){
        int row = r0 + i;
        if (row < 3*NN) dst[row*H + c] = acc[i];
    }
}

// ---------------- update / mixing MLP + final writes ----------------
__global__ __launch_bounds__(256) void update_kernel(float* __restrict__ s, float* __restrict__ v,
                                                     const float* __restrict__ vl, const float* __restrict__ vr,
                                                     const float* __restrict__ mW1, const float* __restrict__ mb1,
                                                     const float* __restrict__ mW2, const float* __restrict__ mb2){
    __shared__ float ts[16][256];
    __shared__ float hid[16][H];
    __shared__ float dotl[16][H];
    int n0 = blockIdx.x * 16;
    int t = threadIdx.x;
    for (int idx = t; idx < 16*H; idx += 256){
        int i = idx >> 7, h = idx & 127;
        int n = n0 + i;
        ts[i][h] = s[n*H + h];
        float l0 = vl[(n*3+0)*H+h], l1 = vl[(n*3+1)*H+h], l2 = vl[(n*3+2)*H+h];
        float r0 = vr[(n*3+0)*H+h], r1 = vr[(n*3+1)*H+h], r2 = vr[(n*3+2)*H+h];
        ts[i][128+h] = sqrtf(l0*l0 + l1*l1 + l2*l2 + 1e-8f);
        dotl[i][h] = l0*r0 + l1*r1 + l2*r2;
    }
    __syncthreads();
    int h = t & 127, g = t >> 7;     // 8 nodes per group
    float acc[8];
    #pragma unroll
    for (int i = 0; i < 8; i++) acc[i] = mb1[h];
    for (int k = 0; k < 256; k++){
        float w = mW1[k*H + h];
        #pragma unroll
        for (int i = 0; i < 8; i++) acc[i] = fmaf(ts[g*8+i][k], w, acc[i]);
    }
    #pragma unroll
    for (int i = 0; i < 8; i++) hid[g*8+i][h] = siluf(acc[i]);
    __syncthreads();
    float m0[8], m1[8], m2[8];
    #pragma unroll
    for (int i = 0; i < 8; i++){ m0[i] = mb2[h]; m1[i] = mb2[128+h]; m2[i] = mb2[256+h]; }
    for (int k = 0; k < H; k++){
        const float* w = mW2 + k*384;
        float w0 = w[h], w1 = w[128+h], w2 = w[256+h];
        #pragma unroll
        for (int i = 0; i < 8; i++){
            float hv = hid[g*8+i][k];
            m0[i] = fmaf(hv, w0, m0[i]);
            m1[i] = fmaf(hv, w1, m1[i]);
            m2[i] = fmaf(hv, w2, m2[i]);
        }
    }
    #pragma unroll
    for (int i = 0; i < 8; i++){
        int n = n0 + g*8 + i;
        s[n*H + h] = ts[g*8+i][h] + clipf(m0[i] + m2[i]*dotl[g*8+i][h]);
        #pragma unroll
        for (int c = 0; c < 3; c++){
            int off = (n*3 + c)*H + h;
            v[off] = v[off] + clipf(m1[i] * vr[off]);
        }
    }
}

extern "C" void kernel_launch(void* const* d_in, const int* in_sizes, int n_in,
                              void* d_out, int out_size, void* d_ws, size_t ws_size,
                              hipStream_t stream) {
    const int*   z    = (const int*)  d_in[0];
    const float* ev   = (const float*)d_in[1];
    const int*   send = (const int*)  d_in[2];
    const int*   recv = (const int*)  d_in[3];
    const float* emb  = (const float*)d_in[4];
    const float* fW   = (const float*)d_in[5];
    const float* fb   = (const float*)d_in[6];
    const float* iW1  = (const float*)d_in[7];
    const float* ib1  = (const float*)d_in[8];
    const float* iW2  = (const float*)d_in[9];
    const float* ib2  = (const float*)d_in[10];
    const float* mW1  = (const float*)d_in[11];
    const float* mb1  = (const float*)d_in[12];
    const float* mW2  = (const float*)d_in[13];
    const float* mb2  = (const float*)d_in[14];
    const float* vW   = (const float*)d_in[15];

    float* s = (float*)d_out;          // [N,H]
    float* v = s + NN*H;               // [N,3,H]

    float* w   = (float*)d_ws;
    float* P   = w;  w += (size_t)24*EE;   // [E][24]
    float* x   = w;  w += NN*384;          // [N,384]
    float* dvn = w;  w += NN*3*H;          // [N,3,H]
    float* vl  = w;  w += NN*3*H;          // [N,3,H]
    float* vr  = w;  w += NN*3*H;          // [N,3,H]
    int* cnt     = (int*)w;
    int* row_ptr = cnt + NN;
    int* cursor  = row_ptr + NN + 1;
    int* order   = cursor + NN;

    // one-time per call: edge features + CSR + embedding
    edge_kernel<<<(EE+255)/256, 256, 0, stream>>>(ev, P);
    hipMemsetAsync(cnt, 0, NN*sizeof(int), stream);
    hist_kernel<<<(EE+255)/256, 256, 0, stream>>>(send, cnt);
    scan_kernel<<<1, 1024, 0, stream>>>(cnt, row_ptr, cursor);
    scatter_kernel<<<(EE+255)/256, 256, 0, stream>>>(send, cursor, order);
    embed_kernel<<<(NN*H+255)/256, 256, 0, stream>>>(z, emb, s);
    hipMemsetAsync(v, 0, (size_t)NN*3*H*sizeof(float), stream);

    for (int l = 0; l < LAYERS; l++){
        xmlp_kernel<<<(NN+31)/32, 256, 0, stream>>>(s, iW1 + l*H*H, ib1 + l*H,
                                                    iW2 + l*H*384, ib2 + l*384, x);
        msg_csr_kernel<<<NN/2, 256, 0, stream>>>(P, x, v, recv, row_ptr, order,
                                                 fW, fb, s, dvn, l);
        vmix_kernel<<<(3*NN+31)/32, 256, 0, stream>>>(v, dvn, vW + l*H*256, vl, vr);
        update_kernel<<<NN/16, 256, 0, stream>>>(s, v, vl, vr,
                                                 mW1 + l*256*H, mb1 + l*H,
                                                 mW2 + l*H*384, mb2 + l*384);
    }
}

// Round 3
// 885.686 us; speedup vs baseline: 1.9437x; 1.3612x over previous
//
#include <hip/hip_runtime.h>
#include <math.h>

#define NN 10000
#define EE 160000
#define H 128
#define LAYERS 3
#define NRBF 20
#define RADIUS 5.0f
#define PI_F 3.14159265358979323846f

__device__ __forceinline__ float clipf(float x){ return fminf(fmaxf(x, -1e4f), 1e4f); }
__device__ __forceinline__ float siluf(float x){ return x / (1.0f + __expf(-x)); }

// ---------------- edge geometry + RBF: row = [dir0,dir1,dir2, phi*cut[0..19], cut] ----------------
__global__ __launch_bounds__(256) void edge_kernel(const float* __restrict__ ev,
                                                   float* __restrict__ P){
    int e = blockIdx.x * 256 + threadIdx.x;
    if (e >= EE) return;
    float x = ev[e*3+0], y = ev[e*3+1], z = ev[e*3+2];
    float d = sqrtf(x*x + y*y + z*z + 1e-8f);
    float inv = 1.0f / d;
    float cut = (d < RADIUS) ? 0.5f * (__cosf(PI_F * d / RADIUS) + 1.0f) : 0.0f;
    float row[24];
    row[0] = x*inv; row[1] = y*inv; row[2] = z*inv;
    #pragma unroll
    for (int k = 0; k < NRBF; k++){
        float mu = RADIUS * (float)k / (float)(NRBF - 1);
        float t = d - mu;
        row[3+k] = __expf(-8.0f * t * t) * cut;   // gamma = 0.5/(R/NRBF)^2 = 8
    }
    row[23] = cut;
    float4* dst = (float4*)(P + (size_t)e*24);
    #pragma unroll
    for (int i = 0; i < 6; i++) dst[i] = ((const float4*)row)[i];
}

// ---------------- CSR build ----------------
__global__ __launch_bounds__(256) void hist_kernel(const int* __restrict__ send, int* __restrict__ cnt){
    int e = blockIdx.x * 256 + threadIdx.x;
    if (e < EE) atomicAdd(&cnt[send[e]], 1);
}

__global__ __launch_bounds__(1024) void scan_kernel(const int* __restrict__ cnt,
                                                    int* __restrict__ row_ptr,
                                                    int* __restrict__ cursor){
    __shared__ int part[1024];
    int t = threadIdx.x;
    int base = t * 10;
    int local[10];
    int sum = 0;
    #pragma unroll
    for (int i = 0; i < 10; i++){
        int idx = base + i;
        local[i] = (idx < NN) ? cnt[idx] : 0;
        sum += local[i];
    }
    part[t] = sum;
    __syncthreads();
    for (int off = 1; off < 1024; off <<= 1){
        int val = (t >= off) ? part[t - off] : 0;
        __syncthreads();
        part[t] += val;
        __syncthreads();
    }
    int run = (t > 0) ? part[t-1] : 0;
    #pragma unroll
    for (int i = 0; i < 10; i++){
        int idx = base + i;
        if (idx < NN){ row_ptr[idx] = run; cursor[idx] = run; run += local[i]; }
    }
    if (t == 1023) row_ptr[NN] = part[1023];
}

__global__ __launch_bounds__(256) void scatter_kernel(const int* __restrict__ send,
                                                      int* __restrict__ cursor,
                                                      int* __restrict__ order){
    int e = blockIdx.x * 256 + threadIdx.x;
    if (e < EE){
        int p = atomicAdd(&cursor[send[e]], 1);
        order[p] = e;
    }
}

// ---------------- embedding ----------------
__global__ __launch_bounds__(256) void embed_kernel(const int* __restrict__ z,
                                                    const float* __restrict__ emb,
                                                    float* __restrict__ s){
    int idx = blockIdx.x * 256 + threadIdx.x;
    if (idx >= NN * H) return;
    int n = idx >> 7, h = idx & 127;
    s[idx] = emb[z[n]*H + h];
}

// ---------------- generic tiled GEMM: out[M][NTOT] = epi(A[M][K] @ W[K][NTOT] + bias) ----------------
// 64x64 tile per block, 256 threads, 4x4 micro-tile per thread.
// MODE 0: A rows from A (stride K). MODE 1: concat — k<128 from A, k>=128 from A2 (both stride 128).
template<int K, int NTOT, bool SILU, bool BIAS, int MODE>
__global__ __launch_bounds__(256) void gemm_kernel(const float* __restrict__ A,
                                                   const float* __restrict__ A2,
                                                   const float* __restrict__ W,
                                                   const float* __restrict__ bias,
                                                   float* __restrict__ out, int M){
    __shared__ float aT[64][64];       // transposed A-tile: aT[k][node]
    int t = threadIdx.x;
    int n0 = blockIdx.x * 64;
    int ng = t & 15;                   // node group (4 nodes)
    int c0 = blockIdx.y * 64 + (t >> 4) * 4;  // 4 cols
    int stg_node = t >> 2;
    int stg_kq   = (t & 3) * 16;

    float acc[4][4];
    float4 bv = make_float4(0.f, 0.f, 0.f, 0.f);
    if (BIAS) bv = *(const float4*)&bias[c0];
    #pragma unroll
    for (int i = 0; i < 4; i++){
        acc[i][0] = bv.x; acc[i][1] = bv.y; acc[i][2] = bv.z; acc[i][3] = bv.w;
    }

    for (int k0 = 0; k0 < K; k0 += 64){
        // stage A^T chunk
        {
            const float* src;
            if (MODE == 0){
                src = A + (size_t)(n0 + stg_node) * K + k0 + stg_kq;
            } else {
                const float* base = (k0 < 128) ? A : A2;
                int ko = (k0 < 128) ? k0 : (k0 - 128);
                src = base + (size_t)(n0 + stg_node) * 128 + ko + stg_kq;
            }
            bool valid = (n0 + stg_node) < M;
            #pragma unroll
            for (int j = 0; j < 4; j++){
                float4 val = valid ? *(const float4*)(src + j*4) : make_float4(0.f,0.f,0.f,0.f);
                int kk = stg_kq + j*4;
                aT[kk+0][stg_node] = val.x;
                aT[kk+1][stg_node] = val.y;
                aT[kk+2][stg_node] = val.z;
                aT[kk+3][stg_node] = val.w;
            }
        }
        __syncthreads();
        const float* wp = W + (size_t)k0 * NTOT + c0;
        #pragma unroll 8
        for (int k = 0; k < 64; k++){
            float4 av = *(const float4*)&aT[k][ng*4];
            float4 wv = *(const float4*)wp;
            wp += NTOT;
            acc[0][0] = fmaf(av.x, wv.x, acc[0][0]);
            acc[0][1] = fmaf(av.x, wv.y, acc[0][1]);
            acc[0][2] = fmaf(av.x, wv.z, acc[0][2]);
            acc[0][3] = fmaf(av.x, wv.w, acc[0][3]);
            acc[1][0] = fmaf(av.y, wv.x, acc[1][0]);
            acc[1][1] = fmaf(av.y, wv.y, acc[1][1]);
            acc[1][2] = fmaf(av.y, wv.z, acc[1][2]);
            acc[1][3] = fmaf(av.y, wv.w, acc[1][3]);
            acc[2][0] = fmaf(av.z, wv.x, acc[2][0]);
            acc[2][1] = fmaf(av.z, wv.y, acc[2][1]);
            acc[2][2] = fmaf(av.z, wv.z, acc[2][2]);
            acc[2][3] = fmaf(av.z, wv.w, acc[2][3]);
            acc[3][0] = fmaf(av.w, wv.x, acc[3][0]);
            acc[3][1] = fmaf(av.w, wv.y, acc[3][1]);
            acc[3][2] = fmaf(av.w, wv.z, acc[3][2]);
            acc[3][3] = fmaf(av.w, wv.w, acc[3][3]);
        }
        __syncthreads();
    }

    #pragma unroll
    for (int i = 0; i < 4; i++){
        int n = n0 + ng*4 + i;
        if (n < M){
            float4 o;
            o.x = SILU ? siluf(acc[i][0]) : acc[i][0];
            o.y = SILU ? siluf(acc[i][1]) : acc[i][1];
            o.z = SILU ? siluf(acc[i][2]) : acc[i][2];
            o.w = SILU ? siluf(acc[i][3]) : acc[i][3];
            *(float4*)&out[(size_t)n * NTOT + c0] = o;
        }
    }
}

// ---------------- message: gather per sender node (no atomics) ----------------
__global__ __launch_bounds__(256) void msg_csr_kernel(const float* __restrict__ P,
                                                      const float* __restrict__ x, const float* __restrict__ v,
                                                      const int* __restrict__ recv,
                                                      const int* __restrict__ row_ptr, const int* __restrict__ order,
                                                      const float* __restrict__ fW, const float* __restrict__ fb,
                                                      float* __restrict__ s, float* __restrict__ dvn, int l){
    int t = threadIdx.x;
    int h = t & 127;
    int n = blockIdx.x * 2 + (t >> 7);
    int col0 = l*384 + h;
    float wf0[NRBF], wf1[NRBF], wf2[NRBF];
    #pragma unroll
    for (int k = 0; k < NRBF; k++){
        const float* w = fW + k*1152 + col0;
        wf0[k] = w[0]; wf1[k] = w[128]; wf2[k] = w[256];
    }
    float b0 = fb[col0], b1 = fb[col0+128], b2 = fb[col0+256];
    if (n >= NN) return;
    int beg = row_ptr[n], end = row_ptr[n+1];
    float ds = 0.0f, dv0 = 0.0f, dv1 = 0.0f, dv2 = 0.0f;
    #pragma unroll 2
    for (int idx = beg; idx < end; idx++){
        int e = order[idx];
        const float4* pe = (const float4*)(P + (size_t)e*24);
        float4 q0 = pe[0], q1 = pe[1], q2 = pe[2], q3 = pe[3], q4 = pe[4], q5 = pe[5];
        int r = recv[e];
        float p[20] = {q0.w, q1.x,q1.y,q1.z,q1.w, q2.x,q2.y,q2.z,q2.w,
                       q3.x,q3.y,q3.z,q3.w, q4.x,q4.y,q4.z,q4.w, q5.x,q5.y,q5.z};
        float cut = q5.w;
        float f0 = b0*cut, f1 = b1*cut, f2 = b2*cut;
        #pragma unroll
        for (int k = 0; k < NRBF; k++){
            f0 = fmaf(p[k], wf0[k], f0);
            f1 = fmaf(p[k], wf1[k], f1);
            f2 = fmaf(p[k], wf2[k], f2);
        }
        const float* xr = x + (size_t)r*384;
        float a = f1 * xr[128 + h];
        float b = f2 * xr[256 + h];
        ds = fmaf(f0, xr[h], ds);
        const float* vr_ = v + (size_t)r*3*H + h;
        dv0 = fmaf(a, q0.x, fmaf(b, vr_[0],   dv0));
        dv1 = fmaf(a, q0.y, fmaf(b, vr_[H],   dv1));
        dv2 = fmaf(a, q0.z, fmaf(b, vr_[2*H], dv2));
    }
    s[n*H + h] += clipf(ds);
    dvn[((size_t)n*3 + 0)*H + h] = dv0;
    dvn[((size_t)n*3 + 1)*H + h] = dv1;
    dvn[((size_t)n*3 + 2)*H + h] = dv2;
}

// ---------------- v += clip(dvn), vectorized ----------------
__global__ __launch_bounds__(256) void vadd_kernel(float* __restrict__ v, const float* __restrict__ dvn){
    int i = blockIdx.x * 256 + threadIdx.x;
    if (i >= 3*NN*H/4) return;
    float4 d = ((const float4*)dvn)[i];
    float4 vv = ((float4*)v)[i];
    vv.x += clipf(d.x); vv.y += clipf(d.y); vv.z += clipf(d.z); vv.w += clipf(d.w);
    ((float4*)v)[i] = vv;
}

// ---------------- vnorm + dot(vl,vr) ----------------
__global__ __launch_bounds__(256) void u1_kernel(const float* __restrict__ vlr,
                                                 float* __restrict__ vnorm, float* __restrict__ dotl){
    int idx = blockIdx.x * 256 + threadIdx.x;
    if (idx >= NN*H) return;
    int n = idx >> 7, h = idx & 127;
    const float* b = vlr + (size_t)n*3*256 + h;
    float l0 = b[0],   l1 = b[256], l2 = b[512];
    float r0 = b[128], r1 = b[384], r2 = b[640];
    vnorm[idx] = sqrtf(l0*l0 + l1*l1 + l2*l2 + 1e-8f);
    dotl[idx]  = l0*r0 + l1*r1 + l2*r2;
}

// ---------------- final update: s += clip(ds2 + dsv*dot), v += clip(dvu*vr) ----------------
__global__ __launch_bounds__(256) void u4_kernel(const float* __restrict__ mm, const float* __restrict__ dotl,
                                                 const float* __restrict__ vlr,
                                                 float* __restrict__ s, float* __restrict__ v){
    int idx = blockIdx.x * 256 + threadIdx.x;
    if (idx >= NN*H) return;
    int n = idx >> 7, h = idx & 127;
    const float* mp = mm + (size_t)n*384;
    float m0 = mp[h], m1 = mp[128+h], m2 = mp[256+h];
    s[idx] += clipf(m0 + m2*dotl[idx]);
    const float* b = vlr + (size_t)n*3*256 + 128 + h;
    float* vb = v + (size_t)n*3*H + h;
    vb[0]     += clipf(m1 * b[0]);
    vb[H]     += clipf(m1 * b[256]);
    vb[2*H]   += clipf(m1 * b[512]);
}

extern "C" void kernel_launch(void* const* d_in, const int* in_sizes, int n_in,
                              void* d_out, int out_size, void* d_ws, size_t ws_size,
                              hipStream_t stream) {
    const int*   z    = (const int*)  d_in[0];
    const float* ev   = (const float*)d_in[1];
    const int*   send = (const int*)  d_in[2];
    const int*   recv = (const int*)  d_in[3];
    const float* emb  = (const float*)d_in[4];
    const float* fW   = (const float*)d_in[5];
    const float* fb   = (const float*)d_in[6];
    const float* iW1  = (const float*)d_in[7];
    const float* ib1  = (const float*)d_in[8];
    const float* iW2  = (const float*)d_in[9];
    const float* ib2  = (const float*)d_in[10];
    const float* mW1  = (const float*)d_in[11];
    const float* mb1  = (const float*)d_in[12];
    const float* mW2  = (const float*)d_in[13];
    const float* mb2  = (const float*)d_in[14];
    const float* vW   = (const float*)d_in[15];

    float* s = (float*)d_out;          // [N,H]
    float* v = s + NN*H;               // [N,3,H]

    float* w     = (float*)d_ws;
    float* P     = w;  w += (size_t)24*EE;     // [E][24]
    float* x     = w;  w += (size_t)NN*384;    // x, later mm
    float* hid   = w;  w += (size_t)NN*H;      // hid, later hid2
    float* dvn   = w;                          // [3N][H] — overlaid by vlr
    float* vlr   = w;  w += (size_t)3*NN*256;  // [3N][256] = [vl|vr]
    float* vnorm = w;  w += (size_t)NN*H;
    float* dotl  = w;  w += (size_t)NN*H;
    int* cnt     = (int*)w;
    int* row_ptr = cnt + NN;
    int* cursor  = row_ptr + NN + 1;
    int* order   = cursor + NN;

    // one-time: edge features + CSR + embedding
    edge_kernel<<<(EE+255)/256, 256, 0, stream>>>(ev, P);
    hipMemsetAsync(cnt, 0, NN*sizeof(int), stream);
    hist_kernel<<<(EE+255)/256, 256, 0, stream>>>(send, cnt);
    scan_kernel<<<1, 1024, 0, stream>>>(cnt, row_ptr, cursor);
    scatter_kernel<<<(EE+255)/256, 256, 0, stream>>>(send, cursor, order);
    embed_kernel<<<(NN*H+255)/256, 256, 0, stream>>>(z, emb, s);
    hipMemsetAsync(v, 0, (size_t)NN*3*H*sizeof(float), stream);

    const int MB = (NN + 63) / 64;      // 157
    const int MB3 = (3*NN + 63) / 64;   // 469

    for (int l = 0; l < LAYERS; l++){
        // x = silu(s@iW1+ib1)@iW2+ib2
        gemm_kernel<128,128,true, true, 0><<<dim3(MB,2), 256, 0, stream>>>(s,   nullptr, iW1 + l*H*H,   ib1 + l*H,   hid, NN);
        gemm_kernel<128,384,false,true, 0><<<dim3(MB,6), 256, 0, stream>>>(hid, nullptr, iW2 + l*H*384, ib2 + l*384, x,   NN);
        // message pass (updates s, writes dvn)
        msg_csr_kernel<<<NN/2, 256, 0, stream>>>(P, x, v, recv, row_ptr, order, fW, fb, s, dvn, l);
        // v += clip(dvn)
        vadd_kernel<<<(3*NN*H/4 + 255)/256, 256, 0, stream>>>(v, dvn);
        // [vl|vr] = v @ vW
        gemm_kernel<128,256,false,false,0><<<dim3(MB3,4), 256, 0, stream>>>(v, nullptr, vW + l*H*256, nullptr, vlr, 3*NN);
        // vnorm, dot
        u1_kernel<<<(NN*H + 255)/256, 256, 0, stream>>>(vlr, vnorm, dotl);
        // mm = silu([s|vnorm]@mW1+mb1)@mW2+mb2   (mm reuses x)
        gemm_kernel<256,128,true, true, 1><<<dim3(MB,2), 256, 0, stream>>>(s,   vnorm,  mW1 + l*256*H, mb1 + l*H,   hid, NN);
        gemm_kernel<128,384,false,true, 0><<<dim3(MB,6), 256, 0, stream>>>(hid, nullptr, mW2 + l*H*384, mb2 + l*384, x,  NN);
        // final updates
        u4_kernel<<<(NN*H + 255)/256, 256, 0, stream>>>(x, dotl, vlr, s, v);
    }
}

// Round 4
// 687.108 us; speedup vs baseline: 2.5054x; 1.2890x over previous
//
#include <hip/hip_runtime.h>
#include <hip/hip_fp16.h>
#include <math.h>

#define NN 10000
#define EE 160000
#define H 128
#define LAYERS 3
#define NRBF 20
#define RADIUS 5.0f
#define PI_F 3.14159265358979323846f

__device__ __forceinline__ float clipf(float x){ return fminf(fmaxf(x, -1e4f), 1e4f); }
__device__ __forceinline__ float siluf(float x){ return x / (1.0f + __expf(-x)); }

struct alignas(16) PH24 { __half h[24]; };   // [dir0,dir1,dir2, phi*cut[0..19], cut]

// ---------------- CSR build ----------------
__global__ __launch_bounds__(256) void hist_kernel(const int* __restrict__ send, int* __restrict__ cnt){
    int e = blockIdx.x * 256 + threadIdx.x;
    if (e < EE) atomicAdd(&cnt[send[e]], 1);
}

__global__ __launch_bounds__(1024) void scan_kernel(const int* __restrict__ cnt,
                                                    int* __restrict__ row_ptr,
                                                    int* __restrict__ cursor){
    __shared__ int part[1024];
    int t = threadIdx.x;
    int base = t * 10;
    int local[10];
    int sum = 0;
    #pragma unroll
    for (int i = 0; i < 10; i++){
        int idx = base + i;
        local[i] = (idx < NN) ? cnt[idx] : 0;
        sum += local[i];
    }
    part[t] = sum;
    __syncthreads();
    for (int off = 1; off < 1024; off <<= 1){
        int val = (t >= off) ? part[t - off] : 0;
        __syncthreads();
        part[t] += val;
        __syncthreads();
    }
    int run = (t > 0) ? part[t-1] : 0;
    #pragma unroll
    for (int i = 0; i < 10; i++){
        int idx = base + i;
        if (idx < NN){ row_ptr[idx] = run; cursor[idx] = run; run += local[i]; }
    }
    if (t == 1023) row_ptr[NN] = part[1023];
}

// scatter + edge features fused: writes P and recv at CSR slot (sequential for msg)
__global__ __launch_bounds__(256) void build_kernel(const float* __restrict__ ev,
                                                    const int* __restrict__ send,
                                                    const int* __restrict__ recv,
                                                    int* __restrict__ cursor,
                                                    int* __restrict__ recv_s,
                                                    __half* __restrict__ Ps){
    int e = blockIdx.x * 256 + threadIdx.x;
    if (e >= EE) return;
    int p = atomicAdd(&cursor[send[e]], 1);
    recv_s[p] = recv[e];
    float x = ev[e*3+0], y = ev[e*3+1], z = ev[e*3+2];
    float d = sqrtf(x*x + y*y + z*z + 1e-8f);
    float inv = 1.0f / d;
    float cut = (d < RADIUS) ? 0.5f * (__cosf(PI_F * d / RADIUS) + 1.0f) : 0.0f;
    PH24 o;
    o.h[0] = __float2half_rn(x*inv);
    o.h[1] = __float2half_rn(y*inv);
    o.h[2] = __float2half_rn(z*inv);
    #pragma unroll
    for (int k = 0; k < NRBF; k++){
        float mu = RADIUS * (float)k / (float)(NRBF - 1);
        float t = d - mu;
        o.h[3+k] = __float2half_rn(__expf(-8.0f * t * t) * cut);
    }
    o.h[23] = __float2half_rn(cut);
    *(PH24*)(Ps + (size_t)p*24) = o;
}

// ---------------- embedding ----------------
__global__ __launch_bounds__(256) void embed_kernel(const int* __restrict__ z,
                                                    const float* __restrict__ emb,
                                                    float* __restrict__ s){
    int idx = blockIdx.x * 256 + threadIdx.x;
    if (idx >= NN * H) return;
    int n = idx >> 7, h = idx & 127;
    s[idx] = emb[z[n]*H + h];
}

// ---------------- generic tiled GEMM ----------------
__device__ __forceinline__ void store4(float* p, float4 o){ *(float4*)p = o; }
__device__ __forceinline__ void store4(__half* p, float4 o){
    ((__half2*)p)[0] = __floats2half2_rn(o.x, o.y);
    ((__half2*)p)[1] = __floats2half2_rn(o.z, o.w);
}

// 64x64 tile per block, 256 threads, 4x4 micro-tile per thread.
// MODE 0: A rows stride K. MODE 1: concat — k<128 from A, k>=128 from A2 (both stride 128).
template<int K, int NTOT, bool SILU, bool BIAS, int MODE, typename OT>
__global__ __launch_bounds__(256) void gemm_kernel(const float* __restrict__ A,
                                                   const float* __restrict__ A2,
                                                   const float* __restrict__ W,
                                                   const float* __restrict__ bias,
                                                   OT* __restrict__ out, int M){
    __shared__ float aT[64][64];
    int t = threadIdx.x;
    int n0 = blockIdx.x * 64;
    int ng = t & 15;
    int c0 = blockIdx.y * 64 + (t >> 4) * 4;
    int stg_node = t >> 2;
    int stg_kq   = (t & 3) * 16;

    float acc[4][4];
    float4 bv = make_float4(0.f, 0.f, 0.f, 0.f);
    if (BIAS) bv = *(const float4*)&bias[c0];
    #pragma unroll
    for (int i = 0; i < 4; i++){
        acc[i][0] = bv.x; acc[i][1] = bv.y; acc[i][2] = bv.z; acc[i][3] = bv.w;
    }

    for (int k0 = 0; k0 < K; k0 += 64){
        {
            const float* src;
            if (MODE == 0){
                src = A + (size_t)(n0 + stg_node) * K + k0 + stg_kq;
            } else {
                const float* base = (k0 < 128) ? A : A2;
                int ko = (k0 < 128) ? k0 : (k0 - 128);
                src = base + (size_t)(n0 + stg_node) * 128 + ko + stg_kq;
            }
            bool valid = (n0 + stg_node) < M;
            #pragma unroll
            for (int j = 0; j < 4; j++){
                float4 val = valid ? *(const float4*)(src + j*4) : make_float4(0.f,0.f,0.f,0.f);
                int kk = stg_kq + j*4;
                aT[kk+0][stg_node] = val.x;
                aT[kk+1][stg_node] = val.y;
                aT[kk+2][stg_node] = val.z;
                aT[kk+3][stg_node] = val.w;
            }
        }
        __syncthreads();
        const float* wp = W + (size_t)k0 * NTOT + c0;
        #pragma unroll 8
        for (int k = 0; k < 64; k++){
            float4 av = *(const float4*)&aT[k][ng*4];
            float4 wv = *(const float4*)wp;
            wp += NTOT;
            acc[0][0] = fmaf(av.x, wv.x, acc[0][0]);
            acc[0][1] = fmaf(av.x, wv.y, acc[0][1]);
            acc[0][2] = fmaf(av.x, wv.z, acc[0][2]);
            acc[0][3] = fmaf(av.x, wv.w, acc[0][3]);
            acc[1][0] = fmaf(av.y, wv.x, acc[1][0]);
            acc[1][1] = fmaf(av.y, wv.y, acc[1][1]);
            acc[1][2] = fmaf(av.y, wv.z, acc[1][2]);
            acc[1][3] = fmaf(av.y, wv.w, acc[1][3]);
            acc[2][0] = fmaf(av.z, wv.x, acc[2][0]);
            acc[2][1] = fmaf(av.z, wv.y, acc[2][1]);
            acc[2][2] = fmaf(av.z, wv.z, acc[2][2]);
            acc[2][3] = fmaf(av.z, wv.w, acc[2][3]);
            acc[3][0] = fmaf(av.w, wv.x, acc[3][0]);
            acc[3][1] = fmaf(av.w, wv.y, acc[3][1]);
            acc[3][2] = fmaf(av.w, wv.z, acc[3][2]);
            acc[3][3] = fmaf(av.w, wv.w, acc[3][3]);
        }
        __syncthreads();
    }

    #pragma unroll
    for (int i = 0; i < 4; i++){
        int n = n0 + ng*4 + i;
        if (n < M){
            float4 o;
            o.x = SILU ? siluf(acc[i][0]) : acc[i][0];
            o.y = SILU ? siluf(acc[i][1]) : acc[i][1];
            o.z = SILU ? siluf(acc[i][2]) : acc[i][2];
            o.w = SILU ? siluf(acc[i][3]) : acc[i][3];
            store4(&out[(size_t)n * NTOT + c0], o);
        }
    }
}

// ---------------- message: gather per sender node, CSR-sequential edge data ----------------
__global__ __launch_bounds__(256) void msg_kernel(const __half* __restrict__ Ps,
                                                  const int* __restrict__ recv_s,
                                                  const int* __restrict__ row_ptr,
                                                  const __half* __restrict__ xh,
                                                  const __half* __restrict__ vh,
                                                  const float* __restrict__ vold,
                                                  const float* __restrict__ fW, const float* __restrict__ fb,
                                                  float* __restrict__ s, float* __restrict__ v2, int l){
    int t = threadIdx.x;
    int h = t & 127;
    int n = blockIdx.x * 2 + (t >> 7);
    int col0 = l*384 + h;
    float wf0[NRBF], wf1[NRBF], wf2[NRBF];
    #pragma unroll
    for (int k = 0; k < NRBF; k++){
        const float* w = fW + k*1152 + col0;
        wf0[k] = w[0]; wf1[k] = w[128]; wf2[k] = w[256];
    }
    float b0 = fb[col0], b1 = fb[col0+128], b2 = fb[col0+256];
    int beg = row_ptr[n], end = row_ptr[n+1];
    float ds = 0.0f, dv0 = 0.0f, dv1 = 0.0f, dv2 = 0.0f;
    #pragma unroll 2
    for (int idx = beg; idx < end; idx++){
        PH24 ph = *(const PH24*)(Ps + (size_t)idx*24);
        int r = recv_s[idx];
        float cut = __half2float(ph.h[23]);
        float f0 = b0*cut, f1 = b1*cut, f2 = b2*cut;
        #pragma unroll
        for (int k = 0; k < NRBF; k++){
            float pk = __half2float(ph.h[3+k]);
            f0 = fmaf(pk, wf0[k], f0);
            f1 = fmaf(pk, wf1[k], f1);
            f2 = fmaf(pk, wf2[k], f2);
        }
        const __half* xr = xh + (size_t)r*384;
        float a = f1 * __half2float(xr[128+h]);
        float b = f2 * __half2float(xr[256+h]);
        ds = fmaf(f0, __half2float(xr[h]), ds);
        const __half* vp = vh + (size_t)r*384;
        dv0 = fmaf(a, __half2float(ph.h[0]), fmaf(b, __half2float(vp[h]),     dv0));
        dv1 = fmaf(a, __half2float(ph.h[1]), fmaf(b, __half2float(vp[128+h]), dv1));
        dv2 = fmaf(a, __half2float(ph.h[2]), fmaf(b, __half2float(vp[256+h]), dv2));
    }
    s[n*H + h] += clipf(ds);
    size_t vb = (size_t)n*384 + h;
    v2[vb]     = vold[vb]     + clipf(dv0);
    v2[vb+128] = vold[vb+128] + clipf(dv1);
    v2[vb+256] = vold[vb+256] + clipf(dv2);
}

// ---------------- vnorm + dot(vl,vr) from fp16 vlr ----------------
__global__ __launch_bounds__(256) void u1_kernel(const __half* __restrict__ vlr,
                                                 float* __restrict__ vnorm, float* __restrict__ dotl){
    int idx = blockIdx.x * 256 + threadIdx.x;
    if (idx >= NN*H) return;
    int n = idx >> 7, h = idx & 127;
    const __half* b = vlr + (size_t)n*768 + h;
    float l0 = __half2float(b[0]),   l1 = __half2float(b[256]), l2 = __half2float(b[512]);
    float r0 = __half2float(b[128]), r1 = __half2float(b[384]), r2 = __half2float(b[640]);
    vnorm[idx] = sqrtf(l0*l0 + l1*l1 + l2*l2 + 1e-8f);
    dotl[idx]  = l0*r0 + l1*r1 + l2*r2;
}

// ---------------- final update: s += clip(ds2+dsv*dot); v_out = v2 + clip(dvu*vr); vh = fp16(v_out) ----------------
__global__ __launch_bounds__(256) void u4_kernel(const float* __restrict__ mm, const float* __restrict__ dotl,
                                                 const __half* __restrict__ vlr, const float* __restrict__ v2,
                                                 float* __restrict__ s, float* __restrict__ v,
                                                 __half* __restrict__ vh){
    int idx = blockIdx.x * 256 + threadIdx.x;
    if (idx >= NN*H) return;
    int n = idx >> 7, h = idx & 127;
    const float* mp = mm + (size_t)n*384;
    float m0 = mp[h], m1 = mp[128+h], m2 = mp[256+h];
    s[idx] += clipf(m0 + m2*dotl[idx]);
    const __half* br = vlr + (size_t)n*768 + 128 + h;
    size_t vb = (size_t)n*384 + h;
    float nv0 = v2[vb]     + clipf(m1 * __half2float(br[0]));
    float nv1 = v2[vb+128] + clipf(m1 * __half2float(br[256]));
    float nv2 = v2[vb+256] + clipf(m1 * __half2float(br[512]));
    v[vb] = nv0;     vh[vb]     = __float2half_rn(nv0);
    v[vb+128] = nv1; vh[vb+128] = __float2half_rn(nv1);
    v[vb+256] = nv2; vh[vb+256] = __float2half_rn(nv2);
}

extern "C" void kernel_launch(void* const* d_in, const int* in_sizes, int n_in,
                              void* d_out, int out_size, void* d_ws, size_t ws_size,
                              hipStream_t stream) {
    const int*   z    = (const int*)  d_in[0];
    const float* ev   = (const float*)d_in[1];
    const int*   send = (const int*)  d_in[2];
    const int*   recv = (const int*)  d_in[3];
    const float* emb  = (const float*)d_in[4];
    const float* fW   = (const float*)d_in[5];
    const float* fb   = (const float*)d_in[6];
    const float* iW1  = (const float*)d_in[7];
    const float* ib1  = (const float*)d_in[8];
    const float* iW2  = (const float*)d_in[9];
    const float* ib2  = (const float*)d_in[10];
    const float* mW1  = (const float*)d_in[11];
    const float* mb1  = (const float*)d_in[12];
    const float* mW2  = (const float*)d_in[13];
    const float* mb2  = (const float*)d_in[14];
    const float* vW   = (const float*)d_in[15];

    float* s = (float*)d_out;          // [N,H]
    float* v = s + NN*H;               // [N,3,H] fp32 state

    char* base = (char*)d_ws;
    __half* Ps    = (__half*)base; base += (size_t)EE*24*2;     // 7.68 MB  CSR-ordered edge feats
    int*    recvs = (int*)base;    base += (size_t)EE*4;        // 0.64 MB
    __half* xh    = (__half*)base;                               // union: x fp16 ...
    float*  mm    = (float*)base;  base += (size_t)NN*384*4;    // ... / mm fp32 (15.36 MB)
    float*  hid   = (float*)base;  base += (size_t)NN*H*4;      // 5.12 MB
    float*  v2    = (float*)base;  base += (size_t)NN*384*4;    // 15.36 MB
    __half* vh    = (__half*)base; base += (size_t)NN*384*2;    // 7.68 MB
    __half* vlr   = (__half*)base; base += (size_t)NN*3*256*2;  // 15.36 MB
    float*  vnorm = (float*)base;  base += (size_t)NN*H*4;      // 5.12 MB
    float*  dotl  = (float*)base;  base += (size_t)NN*H*4;      // 5.12 MB
    int* cnt      = (int*)base;    base += (size_t)NN*4;
    int* row_ptr  = (int*)base;    base += (size_t)(NN+1)*4;
    int* cursor   = (int*)base;

    // one-time: CSR + edge features + embedding + zero v
    hipMemsetAsync(cnt, 0, NN*sizeof(int), stream);
    hist_kernel<<<(EE+255)/256, 256, 0, stream>>>(send, cnt);
    scan_kernel<<<1, 1024, 0, stream>>>(cnt, row_ptr, cursor);
    build_kernel<<<(EE+255)/256, 256, 0, stream>>>(ev, send, recv, cursor, recvs, Ps);
    embed_kernel<<<(NN*H+255)/256, 256, 0, stream>>>(z, emb, s);
    hipMemsetAsync(v,  0, (size_t)NN*384*sizeof(float), stream);
    hipMemsetAsync(vh, 0, (size_t)NN*384*sizeof(__half), stream);

    const int MB  = (NN  + 63) / 64;     // 157
    const int MB3 = (3*NN + 63) / 64;    // 469

    for (int l = 0; l < LAYERS; l++){
        // x = silu(s@iW1+ib1)@iW2+ib2  -> fp16
        gemm_kernel<128,128,true, true, 0,float ><<<dim3(MB,2), 256, 0, stream>>>(s,   nullptr, iW1 + l*H*H,   ib1 + l*H,   hid, NN);
        gemm_kernel<128,384,false,true, 0,__half><<<dim3(MB,6), 256, 0, stream>>>(hid, nullptr, iW2 + l*H*384, ib2 + l*384, xh,  NN);
        // message: s += clip(ds); v2 = v + clip(dv)
        msg_kernel<<<NN/2, 256, 0, stream>>>(Ps, recvs, row_ptr, xh, vh, v, fW, fb, s, v2, l);
        // [vl|vr] = v2 @ vW  -> fp16
        gemm_kernel<128,256,false,false,0,__half><<<dim3(MB3,4), 256, 0, stream>>>(v2, nullptr, vW + l*H*256, nullptr, vlr, 3*NN);
        u1_kernel<<<(NN*H + 255)/256, 256, 0, stream>>>(vlr, vnorm, dotl);
        // mm = silu([s|vnorm]@mW1+mb1)@mW2+mb2
        gemm_kernel<256,128,true, true, 1,float ><<<dim3(MB,2), 256, 0, stream>>>(s,   vnorm,  mW1 + l*256*H, mb1 + l*H,   hid, NN);
        gemm_kernel<128,384,false,true, 0,float ><<<dim3(MB,6), 256, 0, stream>>>(hid, nullptr, mW2 + l*H*384, mb2 + l*384, mm, NN);
        // final updates (also refresh vh for next layer)
        u4_kernel<<<(NN*H + 255)/256, 256, 0, stream>>>(mm, dotl, vlr, v2, s, v, vh);
    }
}

// Round 5
// 586.218 us; speedup vs baseline: 2.9366x; 1.1721x over previous
//
#include <hip/hip_runtime.h>
#include <math.h>

#define NN 10000
#define EE 160000
#define H 128
#define LAYERS 3
#define NRBF 20
#define RADIUS 5.0f
#define PI_F 3.14159265358979323846f

using f16    = _Float16;
using half8  = __attribute__((ext_vector_type(8)))  _Float16;
using f32x16 = __attribute__((ext_vector_type(16))) float;

__device__ __forceinline__ float clipf(float x){ return fminf(fmaxf(x, -1e4f), 1e4f); }
__device__ __forceinline__ float siluf(float x){ return x / (1.0f + __expf(-x)); }

// ---------------- CSR build ----------------
__global__ __launch_bounds__(256) void hist_kernel(const int* __restrict__ send, int* __restrict__ cnt){
    int e = blockIdx.x * 256 + threadIdx.x;
    if (e < EE) atomicAdd(&cnt[send[e]], 1);
}

__global__ __launch_bounds__(1024) void scan_kernel(const int* __restrict__ cnt,
                                                    int* __restrict__ row_ptr,
                                                    int* __restrict__ cursor){
    __shared__ int part[1024];
    int t = threadIdx.x;
    int base = t * 10;
    int local[10];
    int sum = 0;
    #pragma unroll
    for (int i = 0; i < 10; i++){
        int idx = base + i;
        local[i] = (idx < NN) ? cnt[idx] : 0;
        sum += local[i];
    }
    part[t] = sum;
    __syncthreads();
    for (int off = 1; off < 1024; off <<= 1){
        int val = (t >= off) ? part[t - off] : 0;
        __syncthreads();
        part[t] += val;
        __syncthreads();
    }
    int run = (t > 0) ? part[t-1] : 0;
    #pragma unroll
    for (int i = 0; i < 10; i++){
        int idx = base + i;
        if (idx < NN){ row_ptr[idx] = run; cursor[idx] = run; run += local[i]; }
    }
    if (t == 1023) row_ptr[NN] = part[1023];
}

// scatter + edge features fused: P row (fp32[24]) at CSR slot: [dir0,dir1,dir2, phi*cut[0..19], cut]
__global__ __launch_bounds__(256) void build_kernel(const float* __restrict__ ev,
                                                    const int* __restrict__ send,
                                                    const int* __restrict__ recv,
                                                    int* __restrict__ cursor,
                                                    int* __restrict__ recv_s,
                                                    float* __restrict__ Ps){
    int e = blockIdx.x * 256 + threadIdx.x;
    if (e >= EE) return;
    int p = atomicAdd(&cursor[send[e]], 1);
    recv_s[p] = recv[e];
    float x = ev[e*3+0], y = ev[e*3+1], z = ev[e*3+2];
    float d = sqrtf(x*x + y*y + z*z + 1e-8f);
    float inv = 1.0f / d;
    float cut = (d < RADIUS) ? 0.5f * (__cosf(PI_F * d / RADIUS) + 1.0f) : 0.0f;
    float o[24];
    o[0] = x*inv; o[1] = y*inv; o[2] = z*inv;
    #pragma unroll
    for (int k = 0; k < NRBF; k++){
        float mu = RADIUS * (float)k / (float)(NRBF - 1);
        float t = d - mu;
        o[3+k] = __expf(-8.0f * t * t) * cut;
    }
    o[23] = cut;
    float4* dst = (float4*)(Ps + (size_t)p*24);
    #pragma unroll
    for (int i = 0; i < 6; i++) dst[i] = ((const float4*)o)[i];
}

// ---------------- weight convert: fp32 [K][N] -> fp16 transposed [N][K], all 5 matrices x 3 layers ----------------
__global__ __launch_bounds__(256) void wconv_kernel(const float* __restrict__ iW1, const float* __restrict__ iW2,
                                                    const float* __restrict__ vW,  const float* __restrict__ mW1,
                                                    const float* __restrict__ mW2,
                                                    f16* __restrict__ iW1T, f16* __restrict__ iW2T,
                                                    f16* __restrict__ vWT,  f16* __restrict__ mW1T,
                                                    f16* __restrict__ mW2T){
    int idx = blockIdx.x*256 + threadIdx.x;
    if (idx >= 3*180224) return;
    int l = idx / 180224;
    int r = idx % 180224;
    float val; f16* dst;
    if (r < 16384){                 // iW1 [128][128]
        int n = r >> 7, k = r & 127;
        val = iW1[l*16384 + k*128 + n]; dst = iW1T + l*16384 + r;
    } else if (r < 65536){          // iW2 [128][384]
        int r2 = r - 16384; int n = r2 >> 7, k = r2 & 127;
        val = iW2[l*49152 + k*384 + n]; dst = iW2T + l*49152 + r2;
    } else if (r < 98304){          // vW [128][256]
        int r2 = r - 65536; int n = r2 >> 7, k = r2 & 127;
        val = vW[l*32768 + k*256 + n]; dst = vWT + l*32768 + r2;
    } else if (r < 131072){         // mW1 [256][128]
        int r2 = r - 98304; int n = r2 >> 8, k = r2 & 255;
        val = mW1[l*32768 + k*128 + n]; dst = mW1T + l*32768 + r2;
    } else {                        // mW2 [128][384]
        int r2 = r - 131072; int n = r2 >> 7, k = r2 & 127;
        val = mW2[l*49152 + k*384 + n]; dst = mW2T + l*49152 + r2;
    }
    *dst = (f16)val;
}

// ---------------- embedding ----------------
__global__ __launch_bounds__(256) void embed_kernel(const int* __restrict__ z,
                                                    const float* __restrict__ emb,
                                                    float* __restrict__ s, f16* __restrict__ sh){
    int idx = blockIdx.x * 256 + threadIdx.x;
    if (idx >= NN * H) return;
    int n = idx >> 7, h = idx & 127;
    float val = emb[z[n]*H + h];
    s[idx] = val;
    sh[idx] = (f16)val;
}

// ---------------- MFMA GEMM: out[M][NTOT] = epi(A[M][K] @ W), W given transposed fp16 WT[NTOT][K] ----------------
// block: 64x64 output tile, 4 waves (2x2), each wave one 32x32 mfma_f32_32x32x16_f16 chain.
// MODE 0: A[M][K] fp16. MODE 1: concat — k<128 from A, k>=128 from A2 (both [M][128] fp16).
template<int K, int NTOT, bool SILU, bool BIAS, int MODE, typename OT>
__global__ __launch_bounds__(256) void mgemm_kernel(const f16* __restrict__ A,
                                                    const f16* __restrict__ A2,
                                                    const f16* __restrict__ WT,
                                                    const float* __restrict__ bias,
                                                    OT* __restrict__ out, int M){
    __shared__ f16 As[64][K+8];
    int t = threadIdx.x;
    int n0 = blockIdx.x * 64;
    // stage A tile (row-major, 16B chunks)
    {
        int row = t >> 2;
        int seg0 = (t & 3) * (K/4);
        bool valid = (n0 + row) < M;
        #pragma unroll
        for (int j = 0; j < K/32; j++){
            int k = seg0 + j*8;
            half8 val = {};
            if (valid){
                if (MODE == 0) val = *(const half8*)(A + (size_t)(n0+row)*K + k);
                else {
                    const f16* base = (k < 128) ? A : A2;
                    int ko = k & 127;
                    val = *(const half8*)(base + (size_t)(n0+row)*128 + ko);
                }
            }
            *(half8*)&As[row][k] = val;
        }
    }
    __syncthreads();
    int lane = t & 63, w = t >> 6;
    int wr = w >> 1, wc = w & 1;
    int arow = wr*32 + (lane & 31);
    int bcol = blockIdx.y*64 + wc*32 + (lane & 31);
    int koff = (lane >> 5) * 8;
    const f16* ap = &As[arow][koff];
    const f16* bp = WT + (size_t)bcol*K + koff;
    f32x16 acc = {};
    #pragma unroll
    for (int kc = 0; kc < K/16; kc++){
        half8 af = *(const half8*)(ap + kc*16);
        half8 bf = *(const half8*)(bp + kc*16);
        acc = __builtin_amdgcn_mfma_f32_32x32x16_f16(af, bf, acc, 0, 0, 0);
    }
    float bv = BIAS ? bias[bcol] : 0.0f;
    int rbase = n0 + wr*32 + 4*(lane>>5);
    #pragma unroll
    for (int r = 0; r < 16; r++){
        int row = rbase + (r&3) + 8*(r>>2);
        if (row < M){
            float val = acc[r] + bv;
            if (SILU) val = siluf(val);
            out[(size_t)row*NTOT + bcol] = (OT)val;
        }
    }
}

// ---------------- message: gather per sender node, CSR-sequential edge data ----------------
__global__ __launch_bounds__(256) void msg_kernel(const float* __restrict__ Ps,
                                                  const int* __restrict__ recv_s,
                                                  const int* __restrict__ row_ptr,
                                                  const f16* __restrict__ xh,
                                                  const f16* __restrict__ vh,
                                                  const float* __restrict__ fW, const float* __restrict__ fb,
                                                  float* __restrict__ s, f16* __restrict__ sh,
                                                  float* __restrict__ v, f16* __restrict__ v2h, int l){
    int t = threadIdx.x;
    int h = t & 127;
    int n = blockIdx.x * 2 + (t >> 7);
    int col0 = l*384 + h;
    float wf0[NRBF], wf1[NRBF], wf2[NRBF];
    #pragma unroll
    for (int k = 0; k < NRBF; k++){
        const float* w = fW + k*1152 + col0;
        wf0[k] = w[0]; wf1[k] = w[128]; wf2[k] = w[256];
    }
    float b0 = fb[col0], b1 = fb[col0+128], b2 = fb[col0+256];
    int beg = row_ptr[n], end = row_ptr[n+1];
    float ds = 0.0f, dv0 = 0.0f, dv1 = 0.0f, dv2 = 0.0f;
    #pragma unroll 2
    for (int idx = beg; idx < end; idx++){
        const float4* pe = (const float4*)(Ps + (size_t)idx*24);
        float4 q0 = pe[0], q1 = pe[1], q2 = pe[2], q3 = pe[3], q4 = pe[4], q5 = pe[5];
        int r = recv_s[idx];
        float p[20] = {q0.w, q1.x,q1.y,q1.z,q1.w, q2.x,q2.y,q2.z,q2.w,
                       q3.x,q3.y,q3.z,q3.w, q4.x,q4.y,q4.z,q4.w, q5.x,q5.y,q5.z};
        float cut = q5.w;
        float f0 = b0*cut, f1 = b1*cut, f2 = b2*cut;
        #pragma unroll
        for (int k = 0; k < NRBF; k++){
            f0 = fmaf(p[k], wf0[k], f0);
            f1 = fmaf(p[k], wf1[k], f1);
            f2 = fmaf(p[k], wf2[k], f2);
        }
        const f16* xr = xh + (size_t)r*384;
        float a = f1 * (float)xr[128+h];
        float b = f2 * (float)xr[256+h];
        ds = fmaf(f0, (float)xr[h], ds);
        const f16* vp = vh + (size_t)r*384;
        dv0 = fmaf(a, q0.x, fmaf(b, (float)vp[h],     dv0));
        dv1 = fmaf(a, q0.y, fmaf(b, (float)vp[128+h], dv1));
        dv2 = fmaf(a, q0.z, fmaf(b, (float)vp[256+h], dv2));
    }
    int si = n*H + h;
    float sv = s[si] + clipf(ds);
    s[si] = sv; sh[si] = (f16)sv;
    size_t vb = (size_t)n*384 + h;
    float nv0 = v[vb]     + clipf(dv0);
    float nv1 = v[vb+128] + clipf(dv1);
    float nv2 = v[vb+256] + clipf(dv2);
    v[vb]     = nv0; v2h[vb]     = (f16)nv0;
    v[vb+128] = nv1; v2h[vb+128] = (f16)nv1;
    v[vb+256] = nv2; v2h[vb+256] = (f16)nv2;
}

// ---------------- vnorm + dot(vl,vr) from fp16 vlr ----------------
__global__ __launch_bounds__(256) void u1_kernel(const f16* __restrict__ vlr,
                                                 f16* __restrict__ vnormh, float* __restrict__ dotl){
    int idx = blockIdx.x * 256 + threadIdx.x;
    if (idx >= NN*H) return;
    int n = idx >> 7, h = idx & 127;
    const f16* b = vlr + (size_t)n*768 + h;
    float l0 = (float)b[0],   l1 = (float)b[256], l2 = (float)b[512];
    float r0 = (float)b[128], r1 = (float)b[384], r2 = (float)b[640];
    vnormh[idx] = (f16)sqrtf(l0*l0 + l1*l1 + l2*l2 + 1e-8f);
    dotl[idx]   = l0*r0 + l1*r1 + l2*r2;
}

// ---------------- final update: s += clip(ds2+dsv*dot); v += clip(dvu*vr); refresh sh, vh ----------------
__global__ __launch_bounds__(256) void u4_kernel(const float* __restrict__ mm, const float* __restrict__ dotl,
                                                 const f16* __restrict__ vlr,
                                                 float* __restrict__ s, f16* __restrict__ sh,
                                                 float* __restrict__ v, f16* __restrict__ vh){
    int idx = blockIdx.x * 256 + threadIdx.x;
    if (idx >= NN*H) return;
    int n = idx >> 7, h = idx & 127;
    const float* mp = mm + (size_t)n*384;
    float m0 = mp[h], m1 = mp[128+h], m2 = mp[256+h];
    float sv = s[idx] + clipf(m0 + m2*dotl[idx]);
    s[idx] = sv; sh[idx] = (f16)sv;
    const f16* br = vlr + (size_t)n*768 + 128 + h;
    size_t vb = (size_t)n*384 + h;
    float nv0 = v[vb]     + clipf(m1 * (float)br[0]);
    float nv1 = v[vb+128] + clipf(m1 * (float)br[256]);
    float nv2 = v[vb+256] + clipf(m1 * (float)br[512]);
    v[vb]     = nv0; vh[vb]     = (f16)nv0;
    v[vb+128] = nv1; vh[vb+128] = (f16)nv1;
    v[vb+256] = nv2; vh[vb+256] = (f16)nv2;
}

extern "C" void kernel_launch(void* const* d_in, const int* in_sizes, int n_in,
                              void* d_out, int out_size, void* d_ws, size_t ws_size,
                              hipStream_t stream) {
    const int*   z    = (const int*)  d_in[0];
    const float* ev   = (const float*)d_in[1];
    const int*   send = (const int*)  d_in[2];
    const int*   recv = (const int*)  d_in[3];
    const float* emb  = (const float*)d_in[4];
    const float* fW   = (const float*)d_in[5];
    const float* fb   = (const float*)d_in[6];
    const float* iW1  = (const float*)d_in[7];
    const float* ib1  = (const float*)d_in[8];
    const float* iW2  = (const float*)d_in[9];
    const float* ib2  = (const float*)d_in[10];
    const float* mW1  = (const float*)d_in[11];
    const float* mb1  = (const float*)d_in[12];
    const float* mW2  = (const float*)d_in[13];
    const float* mb2  = (const float*)d_in[14];
    const float* vW   = (const float*)d_in[15];

    float* s = (float*)d_out;          // [N,H] fp32 state
    float* v = s + NN*H;               // [N,3,H] fp32 state (updated in place)

    char* base = (char*)d_ws;
    float* Ps     = (float*)base; base += (size_t)EE*24*4;      // 15.36 MB
    int*   recvs  = (int*)base;   base += (size_t)EE*4;         // 0.64 MB
    f16*   xh     = (f16*)base;                                  // union: xh fp16 [N][384]
    float* mm     = (float*)base; base += (size_t)NN*384*4;     // ... / mm fp32 (15.36 MB)
    f16*   hidh   = (f16*)base;   base += (size_t)NN*128*2;     // 2.56 MB
    f16*   v2h    = (f16*)base;   base += (size_t)NN*384*2;     // 7.68 MB
    f16*   vh     = (f16*)base;   base += (size_t)NN*384*2;     // 7.68 MB
    f16*   vlr    = (f16*)base;   base += (size_t)NN*768*2;     // 15.36 MB
    f16*   vnormh = (f16*)base;   base += (size_t)NN*128*2;     // 2.56 MB
    float* dotl   = (float*)base; base += (size_t)NN*128*4;     // 5.12 MB
    f16*   sh     = (f16*)base;   base += (size_t)NN*128*2;     // 2.56 MB
    f16*   iW1T   = (f16*)base;   base += (size_t)3*16384*2;
    f16*   iW2T   = (f16*)base;   base += (size_t)3*49152*2;
    f16*   vWT    = (f16*)base;   base += (size_t)3*32768*2;
    f16*   mW1T   = (f16*)base;   base += (size_t)3*32768*2;
    f16*   mW2T   = (f16*)base;   base += (size_t)3*49152*2;
    int* cnt      = (int*)base;   base += (size_t)NN*4;
    int* row_ptr  = (int*)base;   base += (size_t)(NN+1)*4;
    int* cursor   = (int*)base;

    // one-time: CSR + edge features + weight convert + embedding + zero v
    hipMemsetAsync(cnt, 0, NN*sizeof(int), stream);
    hist_kernel<<<(EE+255)/256, 256, 0, stream>>>(send, cnt);
    scan_kernel<<<1, 1024, 0, stream>>>(cnt, row_ptr, cursor);
    build_kernel<<<(EE+255)/256, 256, 0, stream>>>(ev, send, recv, cursor, recvs, Ps);
    wconv_kernel<<<(3*180224+255)/256, 256, 0, stream>>>(iW1, iW2, vW, mW1, mW2,
                                                         iW1T, iW2T, vWT, mW1T, mW2T);
    embed_kernel<<<(NN*H+255)/256, 256, 0, stream>>>(z, emb, s, sh);
    hipMemsetAsync(v, 0, (size_t)NN*384*sizeof(float), stream);
    hipMemsetAsync(vh, 0, (size_t)NN*384*sizeof(f16), stream);

    const int MB  = (NN  + 63) / 64;     // 157
    const int MB3 = (3*NN + 63) / 64;    // 469

    for (int l = 0; l < LAYERS; l++){
        // x = silu(s@iW1+ib1)@iW2+ib2 -> fp16
        mgemm_kernel<128,128,true, true, 0,f16  ><<<dim3(MB,2), 256, 0, stream>>>(sh,   nullptr, iW1T + l*16384, ib1 + l*H,   hidh, NN);
        mgemm_kernel<128,384,false,true, 0,f16  ><<<dim3(MB,6), 256, 0, stream>>>(hidh, nullptr, iW2T + l*49152, ib2 + l*384, xh,   NN);
        // message: s += clip(ds); v += clip(dv) in place; refresh sh, v2h
        msg_kernel<<<NN/2, 256, 0, stream>>>(Ps, recvs, row_ptr, xh, vh, fW, fb, s, sh, v, v2h, l);
        // [vl|vr] = v @ vW -> fp16
        mgemm_kernel<128,256,false,false,0,f16  ><<<dim3(MB3,4), 256, 0, stream>>>(v2h, nullptr, vWT + l*32768, nullptr, vlr, 3*NN);
        u1_kernel<<<(NN*H + 255)/256, 256, 0, stream>>>(vlr, vnormh, dotl);
        // mm = silu([s|vnorm]@mW1+mb1)@mW2+mb2
        mgemm_kernel<256,128,true, true, 1,f16  ><<<dim3(MB,2), 256, 0, stream>>>(sh,   vnormh,  mW1T + l*32768, mb1 + l*H,   hidh, NN);
        mgemm_kernel<128,384,false,true, 0,float><<<dim3(MB,6), 256, 0, stream>>>(hidh, nullptr, mW2T + l*49152, mb2 + l*384, mm,  NN);
        // final updates (refresh sh, vh)
        u4_kernel<<<(NN*H + 255)/256, 256, 0, stream>>>(mm, dotl, vlr, s, sh, v, vh);
    }
}